// Round 2
// baseline (347.915 us; speedup 1.0000x reference)
//
#include <hip/hip_runtime.h>

#define B_ 16
#define C_ 1024
#define D_ 1024
#define H_ 64
#define M_ (B_*C_)   // 16384

typedef __attribute__((ext_vector_type(8))) short bf16x8;
typedef __attribute__((ext_vector_type(8))) unsigned short ushortx8;
typedef __attribute__((ext_vector_type(4))) float f32x4;

__device__ __forceinline__ float wave_max(float v){
  #pragma unroll
  for (int o = 32; o > 0; o >>= 1) v = fmaxf(v, __shfl_xor(v, o));
  return v;
}
__device__ __forceinline__ float wave_sum(float v){
  #pragma unroll
  for (int o = 32; o > 0; o >>= 1) v += __shfl_xor(v, o);
  return v;
}

// fp32 -> bf16 (RNE)
__device__ __forceinline__ ushort f2bf(float f){
  union { float f; unsigned u; } a; a.f = f;
  unsigned r = a.u + 0x7fff + ((a.u >> 16) & 1);
  return (ushort)(r >> 16);
}
__device__ __forceinline__ float bf2f(ushort h){
  union { unsigned u; float f; } a; a.u = ((unsigned)h) << 16; return a.f;
}

// async global->LDS, 16 B per lane; LDS dest is wave-uniform base + lane*16.
__device__ __forceinline__ void lds_cp16(const ushort* g, ushort* l){
  __builtin_amdgcn_global_load_lds(
      (const __attribute__((address_space(1))) void*)g,
      (__attribute__((address_space(3))) void*)l, 16, 0, 0);
}

// ---------------- merged prep: cvt(x) + weight transposes -----------------
__global__ __launch_bounds__(256) void prep_kernel(
    const float* __restrict__ x, const float* __restrict__ Wf,
    const float* __restrict__ Wg, const float* __restrict__ Wx,
    const float* __restrict__ W1,
    ushort* __restrict__ x_bf, ushort* __restrict__ wt,
    ushort* __restrict__ w1t)
{
  __shared__ float tile[32][33];
  const int blk = blockIdx.x;
  const int t = threadIdx.x;
  if (blk < 16384) {                       // cvt: x -> bf16, 4 elems/thread
    const int i = blk*256 + t;
    float4 v = ((const float4*)x)[i];
    ushort4 o;
    o.x = f2bf(v.x); o.y = f2bf(v.y); o.z = f2bf(v.z); o.w = f2bf(v.w);
    ((ushort4*)x_bf)[i] = o;
  } else if (blk < 16384 + 3072) {         // tconv of Wf/Wg/Wx -> wt[z]
    const int bb = blk - 16384;
    const int z = bb >> 10, rem = bb & 1023;
    const int n0 = (rem & 31)*32, k0 = (rem >> 5)*32;
    const float* W = (z == 0) ? Wf : (z == 1) ? Wg : Wx;
    ushort* Out = wt + (size_t)z*D_*D_;
    const int tx = t & 31, ty = t >> 5;
    #pragma unroll
    for (int i = 0; i < 32; i += 8)
      tile[ty+i][tx] = W[(size_t)(k0+ty+i)*D_ + n0+tx];
    __syncthreads();
    #pragma unroll
    for (int i = 0; i < 32; i += 8)
      Out[(size_t)(n0+ty+i)*D_ + k0+tx] = f2bf(tile[tx][ty+i]);
  } else {                                 // tconv of W1 (1024x64) -> w1t
    const int bb = blk - 16384 - 3072;
    const int n0 = (bb & 1)*32, k0 = (bb >> 1)*32;
    const int tx = t & 31, ty = t >> 5;
    #pragma unroll
    for (int i = 0; i < 32; i += 8)
      tile[ty+i][tx] = W1[(size_t)(k0+ty+i)*H_ + n0+tx];
    __syncthreads();
    #pragma unroll
    for (int i = 0; i < 32; i += 8)
      w1t[(size_t)(n0+ty+i)*D_ + k0+tx] = f2bf(tile[tx][ty+i]);
  }
}

// ---------------- merged QKV projection: pipelined 256^2 NT GEMM ----------
// 256x256 tile, BK=32, 512 thr = 8 waves (2M x 4N), per-wave output 128x64.
// Register-double-buffered fragments: ds_reads for stage p+1 overlap the
// MFMA of stage p (compiler emits counted lgkmcnt). Exactly 2 s_barriers
// per K-tile (RAW landing + WAR recycle), counted vmcnt(6) once per tile,
// 4-deep LDS rotation, setprio around MFMA clusters.
__global__ __launch_bounds__(512, 2) void proj_kernel(
    const ushort* __restrict__ A, const ushort* __restrict__ Wt,
    const float* __restrict__ bf, const float* __restrict__ bg,
    const float* __restrict__ bx,
    ushort* __restrict__ q, ushort* __restrict__ k, ushort* __restrict__ v)
{
  __shared__ ushort As[4][8192];   // 4 buf x 256 rows x 32 (64 KB)
  __shared__ ushort Bs[4][8192];   // 4 buf x 256 rows x 32 (64 KB)
  const int t = threadIdx.x;          // 0..511
  const int lane = t & 63;
  const int wid  = t >> 6;            // 0..7
  const int wm = wid >> 2;            // 0..1  (m half)
  const int wn = wid & 3;             // 0..3  (n quarter)

  // block -> tile via chunked XCD swizzle (768 = 8 XCDs x 96, bijective)
  const int wg = blockIdx.x;
  const int sw = (wg & 7) * 96 + (wg >> 3);
  const int mI = sw / 12, nI = sw - mI*12;
  const int m0 = mI * 256, n0 = nI * 256;     // n0 in [0,3072)
  const int seg = n0 >> 10;                   // 0:q 1:k 2:v
  const int nloc0 = n0 & 1023;

  // staging: thread t loads 16B: row t>>2 (of 128), phys chunk t&3.
  // global source column pre-swizzled so LDS read side XORs the same way.
  const int srow = t >> 2;                    // 0..127
  const int sfr  = (srow >> 1) & 3;
  const int schunk = ((t & 3) ^ sfr) * 8;     // element offset in k-window
  const ushort* gA0 = A  + (size_t)(m0 + srow)*1024 + schunk;       // rows 0-127
  const ushort* gA1 = gA0 + (size_t)128*1024;                        // rows 128-255
  const ushort* gB0 = Wt + (size_t)(n0 + srow)*1024 + schunk;
  const ushort* gB1 = gB0 + (size_t)128*1024;
  const int ldst = t * 8;                     // linear LDS slot (16B/thread)

  const int quad = lane >> 4, l16 = lane & 15;
  const int fr4 = (l16 >> 1) & 3;
  const int aoff = (wm*128 + l16)*32 + ((quad ^ fr4) * 8);
  const int boff = (wn*64  + l16)*32 + ((quad ^ fr4) * 8);

  f32x4 acc[8][4] = {};

  // prologue: stage K-tiles 0,1,2 (4 loads each: A0,A1,B0,B1, in order)
  #pragma unroll
  for (int tt = 0; tt < 3; ++tt) {
    const int ko = tt * 32;
    lds_cp16(gA0 + ko, &As[tt][ldst]);
    lds_cp16(gA1 + ko, &As[tt][4096 + ldst]);
    lds_cp16(gB0 + ko, &Bs[tt][ldst]);
    lds_cp16(gB1 + ko, &Bs[tt][4096 + ldst]);
  }
  asm volatile("s_waitcnt vmcnt(8)" ::: "memory");   // tile 0 landed
  asm volatile("s_barrier" ::: "memory");

  // preload tile-0 fragments: B frags + A frags for m-tiles 0-3
  bf16x8 cbf[4], ca0[4], nbf[4], na0[4];
  #pragma unroll
  for (int i = 0; i < 4; ++i) cbf[i] = *(const bf16x8*)&Bs[0][boff + i*512];
  #pragma unroll
  for (int i = 0; i < 4; ++i) ca0[i] = *(const bf16x8*)&As[0][aoff + i*512];

  for (int t0 = 0; t0 < 32; ++t0) {
    const ushort* Ab  = As[t0 & 3];
    const ushort* AbN = As[(t0 + 1) & 3];
    const ushort* BbN = Bs[(t0 + 1) & 3];
    const int nxt = (t0 + 3) & 3;               // recycles buf (t0-1)&3
    const int ko  = (t0 + 3) * 32;

    // stage A-half of tile t0+3 (WAR-safe: after B_end of tile t0-1)
    if (t0 < 29) {
      lds_cp16(gA0 + ko, &As[nxt][ldst]);
      lds_cp16(gA1 + ko, &As[nxt][4096 + ldst]);
    }
    // counted drain: tile t0+1's 4 loads complete; rest stay in flight
    if (t0 < 29)       asm volatile("s_waitcnt vmcnt(6)" ::: "memory");
    else if (t0 == 29) asm volatile("s_waitcnt vmcnt(4)" ::: "memory");
    else if (t0 == 30) asm volatile("s_waitcnt vmcnt(0)" ::: "memory");
    asm volatile("s_barrier" ::: "memory");      // B_mid: buf(t0+1) published

    // ---- phase 0: read af1(t0) UNDER the MFMA of m-tiles 0-3
    bf16x8 ca1[4];
    #pragma unroll
    for (int i = 0; i < 4; ++i) ca1[i] = *(const bf16x8*)&Ab[aoff + 2048 + i*512];
    __builtin_amdgcn_sched_barrier(0);
    __builtin_amdgcn_s_setprio(1);
    #pragma unroll
    for (int mt = 0; mt < 4; ++mt)
      #pragma unroll
      for (int nt = 0; nt < 4; ++nt)
        acc[mt][nt] = __builtin_amdgcn_mfma_f32_16x16x32_bf16(
            ca0[mt], cbf[nt], acc[mt][nt], 0, 0, 0);
    __builtin_amdgcn_s_setprio(0);

    // ---- phase 1: stage B-half of t0+3; read next-tile frags UNDER MFMA
    if (t0 < 29) {
      lds_cp16(gB0 + ko, &Bs[nxt][ldst]);
      lds_cp16(gB1 + ko, &Bs[nxt][4096 + ldst]);
    }
    if (t0 < 31) {
      #pragma unroll
      for (int i = 0; i < 4; ++i) nbf[i] = *(const bf16x8*)&BbN[boff + i*512];
      #pragma unroll
      for (int i = 0; i < 4; ++i) na0[i] = *(const bf16x8*)&AbN[aoff + i*512];
    }
    __builtin_amdgcn_sched_barrier(0);
    __builtin_amdgcn_s_setprio(1);
    #pragma unroll
    for (int mt = 0; mt < 4; ++mt)
      #pragma unroll
      for (int nt = 0; nt < 4; ++nt)
        acc[4+mt][nt] = __builtin_amdgcn_mfma_f32_16x16x32_bf16(
            ca1[mt], cbf[nt], acc[4+mt][nt], 0, 0, 0);
    __builtin_amdgcn_s_setprio(0);
    asm volatile("s_barrier" ::: "memory");      // B_end: all reads of t0 drained

    // rotate register buffers
    #pragma unroll
    for (int i = 0; i < 4; ++i) { cbf[i] = nbf[i]; ca0[i] = na0[i]; }
  }

  // epilogue: bias + ReLU + bf16 store
  const float* bp = (seg == 0) ? bf : (seg == 1) ? bg : bx;
  ushort* op      = (seg == 0) ? q  : (seg == 1) ? k  : v;
  const int gm_base = m0 + wm*128 + quad*4;
  const int gn_base = nloc0 + wn*64 + l16;
  float bv[4];
  #pragma unroll
  for (int nt = 0; nt < 4; ++nt) bv[nt] = bp[gn_base + nt*16];
  #pragma unroll
  for (int mt = 0; mt < 8; ++mt)
    #pragma unroll
    for (int rr = 0; rr < 4; ++rr) {
      const size_t rowoff = (size_t)(gm_base + mt*16 + rr) * 1024;
      #pragma unroll
      for (int nt = 0; nt < 4; ++nt)
        op[rowoff + gn_base + nt*16] =
            f2bf(fmaxf(acc[mt][nt][rr] + bv[nt], 0.f));
    }
}

// ---------------- energy: NT GEMM, 64x128 tile, BK=64, 4 blocks/CU --------
// Grid = 16x8x16 = 2048 blocks; at 4/CU -> 1024 co-resident = exactly 2
// scheduling rounds. Wave w owns n-cols [w*32, w*32+32).
__global__ __launch_bounds__(256, 4) void energy_kernel(
    const ushort* __restrict__ Km, const ushort* __restrict__ Qm,
    ushort* __restrict__ E)
{
  __shared__ ushort As[64*64];    // [m(j) row][k]
  __shared__ ushort Bs[128*64];   // [n(i) row][k]
  const int t = threadIdx.x;
  const int wid = t >> 6, lane = t & 63;
  const int m0 = blockIdx.y * 64, n0 = blockIdx.x * 128;
  const int bz = blockIdx.z;
  const ushort* Ab = Km + (size_t)bz * C_ * D_;
  const ushort* Bb = Qm + (size_t)bz * C_ * D_;

  const int srow = t >> 3;                      // 0..31
  const int sch = ((t & 7) ^ (srow & 7)) * 8;   // +32 rows keeps row&7
  const ushort* gaBase = Ab + (size_t)(m0 + srow)*1024 + sch;
  const ushort* gbBase = Bb + (size_t)(n0 + srow)*1024 + sch;

  const int quad = lane >> 4, l16 = lane & 15;
  const int cx0 = ((0*4 + quad) ^ (l16 & 7)) * 8;
  const int cx1 = ((1*4 + quad) ^ (l16 & 7)) * 8;
  const int brow0 = (wid*32 + l16)*64;

  f32x4 acc[4][2] = {};

  for (int k0 = 0; k0 < 1024; k0 += 64) {
    // A: 64 rows -> 2 issues; B: 128 rows -> 4 issues
    #pragma unroll
    for (int i = 0; i < 2; ++i)
      lds_cp16(gaBase + (size_t)(i*32)*1024, As + (8*wid + 32*i)*64);
    #pragma unroll
    for (int i = 0; i < 4; ++i)
      lds_cp16(gbBase + (size_t)(i*32)*1024, Bs + (8*wid + 32*i)*64);
    gaBase += 64; gbBase += 64;
    __syncthreads();
    #pragma unroll
    for (int h = 0; h < 2; ++h) {
      const int cx = h ? cx1 : cx0;
      bf16x8 af[4], bfr[2];
      #pragma unroll
      for (int i = 0; i < 4; ++i)
        af[i] = *(const bf16x8*)&As[(i*16 + l16)*64 + cx];
      #pragma unroll
      for (int i = 0; i < 2; ++i)
        bfr[i] = *(const bf16x8*)&Bs[brow0 + i*16*64 + cx];
      #pragma unroll
      for (int mt = 0; mt < 4; ++mt)
        #pragma unroll
        for (int nt = 0; nt < 2; ++nt)
          acc[mt][nt] = __builtin_amdgcn_mfma_f32_16x16x32_bf16(
              af[mt], bfr[nt], acc[mt][nt], 0, 0, 0);
    }
    __syncthreads();
  }

  ushort* O = E + (size_t)bz * C_ * C_;
  const int gm_base = m0 + quad*4;              // j row
  const int gn_base = n0 + wid*32 + l16;        // i col
  #pragma unroll
  for (int mt = 0; mt < 4; ++mt)
    #pragma unroll
    for (int rr = 0; rr < 4; ++rr) {
      const size_t rowoff = (size_t)(gm_base + mt*16 + rr) * 1024;
      #pragma unroll
      for (int nt = 0; nt < 2; ++nt)
        O[rowoff + gn_base + nt*16] = f2bf(acc[mt][nt][rr]);
    }
}

// ---------------- pooling MLP via MFMA (BK=32) ----------------------------
__device__ __forceinline__ int fsw(int row){
  return (row & 3) ^ ((row >> 2) & 3);
}
__global__ __launch_bounds__(256) void pool_mfma_kernel(
    const ushort* __restrict__ A, const ushort* __restrict__ Bt,
    const float* __restrict__ b1, const float* __restrict__ W2,
    float* __restrict__ e2out)
{
  __shared__ ushort As[128*32];
  __shared__ ushort Bs[64*32];
  const int t = threadIdx.x;
  const int wid = t >> 6, lane = t & 63;
  const int m0 = blockIdx.x * 128;

  const int r = t >> 2;
  const int kc = ((t & 3) ^ fsw(r)) * 8;
  const ushort* ga0 = A + (size_t)(m0 + r)*1024 + kc;
  const ushort* ga1 = ga0 + (size_t)64*1024;
  const ushort* gb0 = Bt + (size_t)r*1024 + kc;
  ushort* lA = As + wid*512;
  ushort* lB = Bs + wid*512;

  const int quad = lane >> 4, l16 = lane & 15;
  const int fr = fsw(l16);
  const int am0 = (wid*32 + l16)*32 + ((quad ^ fr)*8);
  const int bn0 = l16*32 + ((quad ^ fr)*8);

  f32x4 acc[2][4] = {};

  for (int k0 = 0; k0 < 1024; k0 += 32) {
    lds_cp16(ga0, lA); lds_cp16(ga1, lA + 2048);
    lds_cp16(gb0, lB);
    ga0 += 32; ga1 += 32; gb0 += 32;
    __syncthreads();
    bf16x8 af[2], bfr[4];
    #pragma unroll
    for (int i = 0; i < 2; ++i) af[i] = *(const bf16x8*)&As[am0 + i*512];
    #pragma unroll
    for (int i = 0; i < 4; ++i) bfr[i] = *(const bf16x8*)&Bs[bn0 + i*512];
    #pragma unroll
    for (int mt = 0; mt < 2; ++mt)
      #pragma unroll
      for (int nt = 0; nt < 4; ++nt)
        acc[mt][nt] = __builtin_amdgcn_mfma_f32_16x16x32_bf16(
            af[mt], bfr[nt], acc[mt][nt], 0, 0, 0);
    __syncthreads();
  }

  float b1v[4], w2v[4];
  #pragma unroll
  for (int nt = 0; nt < 4; ++nt) {
    b1v[nt] = b1[nt*16 + l16];
    w2v[nt] = W2[nt*16 + l16];
  }
  #pragma unroll
  for (int mt = 0; mt < 2; ++mt)
    #pragma unroll
    for (int rr = 0; rr < 4; ++rr) {
      float h = 0.f;
      #pragma unroll
      for (int nt = 0; nt < 4; ++nt)
        h += fmaxf(acc[mt][nt][rr] + b1v[nt], 0.f) * w2v[nt];
      #pragma unroll
      for (int o = 1; o < 16; o <<= 1) h += __shfl_xor(h, o);
      if (l16 == 0)
        e2out[m0 + wid*32 + mt*16 + quad*4 + rr] = h;
    }
}

// ---------------- fused row-softmax + weighted column-sum (bf16 E) --------
__global__ __launch_bounds__(256) void fused_sm_kernel(
    const ushort* __restrict__ E, const float* __restrict__ w,
    float* __restrict__ u_part)
{
  __shared__ float ul[4][1024];
  const int b = blockIdx.y;
  const int strip = blockIdx.x;       // 0..63
  const int t = threadIdx.x, wv = t >> 6, lane = t & 63;
  const ushort* Eb = E + (size_t)b*C_*C_;
  const float* wb = w + (size_t)b*C_;
  float acc[2][8] = {};               // i = c*512 + lane*8 + k
  #pragma unroll
  for (int rj = 0; rj < 4; ++rj) {
    const int j = strip*16 + wv*4 + rj;
    const ushort* row = Eb + (size_t)j*C_;
    float vv[2][8];
    float m = -1e30f;
    #pragma unroll
    for (int c = 0; c < 2; ++c) {
      ushortx8 h = *(const ushortx8*)&row[c*512 + lane*8];
      #pragma unroll
      for (int kk = 0; kk < 8; ++kk) {
        vv[c][kk] = bf2f(h[kk]);
        m = fmaxf(m, vv[c][kk]);
      }
    }
    m = wave_max(m);
    float e[2][8];
    float s = 0.f;
    #pragma unroll
    for (int c = 0; c < 2; ++c)
      #pragma unroll
      for (int kk = 0; kk < 8; ++kk) {
        e[c][kk] = expf(vv[c][kk] - m);
        s += e[c][kk];
      }
    s = wave_sum(s);
    const float sc = wb[j] / s;
    #pragma unroll
    for (int c = 0; c < 2; ++c)
      #pragma unroll
      for (int kk = 0; kk < 8; ++kk) acc[c][kk] += sc * e[c][kk];
  }
  #pragma unroll
  for (int c = 0; c < 2; ++c)
    #pragma unroll
    for (int k4 = 0; k4 < 2; ++k4) {
      float4 o;
      o.x = acc[c][k4*4+0]; o.y = acc[c][k4*4+1];
      o.z = acc[c][k4*4+2]; o.w = acc[c][k4*4+3];
      *(float4*)&ul[wv][c*512 + lane*8 + k4*4] = o;
    }
  __syncthreads();
  float4 r0 = *(float4*)&ul[0][t*4];
  float4 r1 = *(float4*)&ul[1][t*4];
  float4 r2 = *(float4*)&ul[2][t*4];
  float4 r3 = *(float4*)&ul[3][t*4];
  float4 o;
  o.x = r0.x+r1.x+r2.x+r3.x; o.y = r0.y+r1.y+r2.y+r3.y;
  o.z = r0.z+r1.z+r2.z+r3.z; o.w = r0.w+r1.w+r2.w+r3.w;
  *(float4*)&u_part[((size_t)strip*B_ + b)*C_ + t*4] = o;
}

// ---------------- pooling softmax ----------------
__global__ __launch_bounds__(256) void softmax_w_kernel(
    const float* __restrict__ e2in, float* __restrict__ w)
{
  __shared__ float redm[4];
  __shared__ float reds[4];
  const int b = blockIdx.x, t = threadIdx.x;
  const int lane = t & 63, wid = t >> 6;
  const float* row = e2in + (size_t)b*C_;
  float4 v = *(const float4*)&row[t*4];
  float m = fmaxf(fmaxf(v.x, v.y), fmaxf(v.z, v.w));
  m = wave_max(m);
  if (lane == 0) redm[wid] = m;
  __syncthreads();
  m = fmaxf(fmaxf(redm[0], redm[1]), fmaxf(redm[2], redm[3]));
  float e0 = expf(v.x - m), e1 = expf(v.y - m);
  float e2 = expf(v.z - m), e3 = expf(v.w - m);
  float s = e0 + e1 + e2 + e3;
  s = wave_sum(s);
  if (lane == 0) reds[wid] = s;
  __syncthreads();
  s = reds[0] + reds[1] + reds[2] + reds[3];
  const float inv = 1.0f / s;
  float4 o; o.x = e0*inv; o.y = e1*inv; o.z = e2*inv; o.w = e3*inv;
  *(float4*)&w[(size_t)b*C_ + t*4] = o;
}

// ---------------- final reduction: u-combine fused in, split over i -------
__global__ __launch_bounds__(256) void final_part_kernel(
    const ushort* __restrict__ X, const ushort* __restrict__ V,
    const float* __restrict__ u_part, const float* __restrict__ w,
    const float* __restrict__ gamma, float* __restrict__ fpart)
{
  const int b = blockIdx.x, s = blockIdx.y;    // i in [s*16, s*16+16)
  const int t = threadIdx.x;
  __shared__ float red[16][17];
  __shared__ float us[16];
  {
    const int ii = t & 15, g = t >> 4;         // g sums 4 strips
    float p = 0.f;
    #pragma unroll
    for (int q2 = 0; q2 < 4; ++q2) {
      const int sp = g*4 + q2;
      p += u_part[((size_t)sp*B_ + b)*C_ + s*16 + ii];
    }
    red[ii][g] = p;
  }
  __syncthreads();
  if (t < 16) {
    float s2 = 0.f;
    #pragma unroll
    for (int g = 0; g < 16; ++g) s2 += red[t][g];
    us[t] = s2;
  }
  __syncthreads();

  const int d0 = t * 4;
  const ushort* xb = X + (size_t)b*C_*D_;
  const ushort* vb = V + (size_t)b*C_*D_;
  const float* wb = w + (size_t)b*C_;
  float4 av = {0,0,0,0}, ax = {0,0,0,0};
  #pragma unroll
  for (int ii = 0; ii < 16; ++ii) {
    const int i = s*16 + ii;
    const float ui = us[ii], wi = wb[i];
    ushort4 vv = *(const ushort4*)&vb[(size_t)i*D_ + d0];
    ushort4 xv = *(const ushort4*)&xb[(size_t)i*D_ + d0];
    av.x += ui*bf2f(vv.x); av.y += ui*bf2f(vv.y);
    av.z += ui*bf2f(vv.z); av.w += ui*bf2f(vv.w);
    ax.x += wi*bf2f(xv.x); ax.y += wi*bf2f(xv.y);
    ax.z += wi*bf2f(xv.z); ax.w += wi*bf2f(xv.w);
  }
  const float g = gamma[0];
  float4 o;
  o.x = g*av.x + ax.x; o.y = g*av.y + ax.y;
  o.z = g*av.z + ax.z; o.w = g*av.w + ax.w;
  *(float4*)&fpart[((size_t)s*B_ + b)*D_ + d0] = o;
}

__global__ __launch_bounds__(256) void final_combine_kernel(
    const float* __restrict__ fpart, float* __restrict__ out)
{
  const int idx = blockIdx.x*256 + threadIdx.x;   // over B_*D_
  float s = 0.f;
  #pragma unroll 8
  for (int sp = 0; sp < 64; ++sp) s += fpart[(size_t)sp*B_*D_ + idx];
  out[idx] = s;
}

extern "C" void kernel_launch(void* const* d_in, const int* in_sizes, int n_in,
                              void* d_out, int out_size, void* d_ws, size_t ws_size,
                              hipStream_t stream) {
  (void)in_sizes; (void)n_in; (void)out_size; (void)ws_size;
  const float* x  = (const float*)d_in[0];
  const float* Wf = (const float*)d_in[1];
  const float* bf = (const float*)d_in[2];
  const float* Wg = (const float*)d_in[3];
  const float* bg = (const float*)d_in[4];
  const float* Wx = (const float*)d_in[5];
  const float* bx = (const float*)d_in[6];
  const float* W1 = (const float*)d_in[7];
  const float* b1 = (const float*)d_in[8];
  const float* W2 = (const float*)d_in[9];
  const float* gamma = (const float*)d_in[11];
  float* out = (float*)d_out;

  // workspace layout (~140 MB total)
  ushort* x_bf = (ushort*)d_ws;                  // 32 MB
  ushort* wt   = x_bf + (size_t)M_*D_;           // 6 MB (Wf^T|Wg^T|Wx^T contiguous)
  ushort* w1t  = wt + (size_t)3*D_*D_;           // 128 KB
  ushort* q_bf = w1t + (size_t)H_*D_;            // 32 MB
  ushort* k_bf = q_bf + (size_t)M_*D_;           // 32 MB
  ushort* v_bf = k_bf + (size_t)M_*D_;           // 32 MB
  ushort* E    = v_bf + (size_t)M_*D_;           // 32 MB (bf16, all batches)
  float*  e2b  = (float*)(E + (size_t)B_*C_*C_); // 64 KB
  float*  wbuf = e2b + M_;                       // 64 KB
  float*  u_part = wbuf + M_;                    // 4 MB
  float*  fpart  = (float*)E;                    // alias: E dead after fused_sm

  // prep: x->bf16 + weight transposes, one launch
  prep_kernel<<<dim3(16384+3072+64), 256, 0, stream>>>(
      x, Wf, Wg, Wx, W1, x_bf, wt, w1t);

  // merged q/k/v projection (256^2 tile pipelined bf16 MFMA, 768 blocks)
  proj_kernel<<<dim3(768), 512, 0, stream>>>(x_bf, wt, bf, bg, bx,
                                             q_bf, k_bf, v_bf);

  // pooling weights (MFMA MLP + softmax)
  pool_mfma_kernel<<<dim3(M_/128), 256, 0, stream>>>(x_bf, w1t, b1, W2, e2b);
  softmax_w_kernel<<<dim3(B_), 256, 0, stream>>>(e2b, wbuf);

  // energy (64x128 tile, 4 blocks/CU, exact 2 rounds) + fused softmax/colsum
  energy_kernel<<<dim3(8,16,B_), 256, 0, stream>>>(k_bf, q_bf, E);
  fused_sm_kernel<<<dim3(64,B_), 256, 0, stream>>>(E, wbuf, u_part);

  // final: u-combine + split-i reduction into fpart, then combine
  final_part_kernel<<<dim3(B_,64), 256, 0, stream>>>(x_bf, v_bf, u_part, wbuf,
                                                     gamma, fpart);
  final_combine_kernel<<<dim3(M_/256), 256, 0, stream>>>(fpart, out);
}

// Round 4
// 338.987 us; speedup vs baseline: 1.0263x; 1.0263x over previous
//
#include <hip/hip_runtime.h>

#define B_ 16
#define C_ 1024
#define D_ 1024
#define H_ 64
#define M_ (B_*C_)   // 16384

typedef __attribute__((ext_vector_type(8))) short bf16x8;
typedef __attribute__((ext_vector_type(8))) unsigned short ushortx8;
typedef __attribute__((ext_vector_type(4))) float f32x4;

__device__ __forceinline__ float wave_max(float v){
  #pragma unroll
  for (int o = 32; o > 0; o >>= 1) v = fmaxf(v, __shfl_xor(v, o));
  return v;
}
__device__ __forceinline__ float wave_sum(float v){
  #pragma unroll
  for (int o = 32; o > 0; o >>= 1) v += __shfl_xor(v, o);
  return v;
}

// fp32 -> bf16 (RNE)
__device__ __forceinline__ ushort f2bf(float f){
  union { float f; unsigned u; } a; a.f = f;
  unsigned r = a.u + 0x7fff + ((a.u >> 16) & 1);
  return (ushort)(r >> 16);
}
__device__ __forceinline__ float bf2f(ushort h){
  union { unsigned u; float f; } a; a.u = ((unsigned)h) << 16; return a.f;
}

// async global->LDS, 16 B per lane; LDS dest is wave-uniform base + lane*16.
__device__ __forceinline__ void lds_cp16(const ushort* g, ushort* l){
  __builtin_amdgcn_global_load_lds(
      (const __attribute__((address_space(1))) void*)g,
      (__attribute__((address_space(3))) void*)l, 16, 0, 0);
}

// ---------------- merged prep: cvt(x) + weight transposes -----------------
__global__ __launch_bounds__(256) void prep_kernel(
    const float* __restrict__ x, const float* __restrict__ Wf,
    const float* __restrict__ Wg, const float* __restrict__ Wx,
    const float* __restrict__ W1,
    ushort* __restrict__ x_bf, ushort* __restrict__ wt,
    ushort* __restrict__ w1t)
{
  __shared__ float tile[32][33];
  const int blk = blockIdx.x;
  const int t = threadIdx.x;
  if (blk < 16384) {                       // cvt: x -> bf16, 4 elems/thread
    const int i = blk*256 + t;
    float4 v = ((const float4*)x)[i];
    ushort4 o;
    o.x = f2bf(v.x); o.y = f2bf(v.y); o.z = f2bf(v.z); o.w = f2bf(v.w);
    ((ushort4*)x_bf)[i] = o;
  } else if (blk < 16384 + 3072) {         // tconv of Wf/Wg/Wx -> wt[z]
    const int bb = blk - 16384;
    const int z = bb >> 10, rem = bb & 1023;
    const int n0 = (rem & 31)*32, k0 = (rem >> 5)*32;
    const float* W = (z == 0) ? Wf : (z == 1) ? Wg : Wx;
    ushort* Out = wt + (size_t)z*D_*D_;
    const int tx = t & 31, ty = t >> 5;
    #pragma unroll
    for (int i = 0; i < 32; i += 8)
      tile[ty+i][tx] = W[(size_t)(k0+ty+i)*D_ + n0+tx];
    __syncthreads();
    #pragma unroll
    for (int i = 0; i < 32; i += 8)
      Out[(size_t)(n0+ty+i)*D_ + k0+tx] = f2bf(tile[tx][ty+i]);
  } else {                                 // tconv of W1 (1024x64) -> w1t
    const int bb = blk - 16384 - 3072;
    const int n0 = (bb & 1)*32, k0 = (bb >> 1)*32;
    const int tx = t & 31, ty = t >> 5;
    #pragma unroll
    for (int i = 0; i < 32; i += 8)
      tile[ty+i][tx] = W1[(size_t)(k0+ty+i)*H_ + n0+tx];
    __syncthreads();
    #pragma unroll
    for (int i = 0; i < 32; i += 8)
      w1t[(size_t)(n0+ty+i)*D_ + k0+tx] = f2bf(tile[tx][ty+i]);
  }
}

// ---------------- merged QKV projection: 256^2, 8-phase m201 schedule -----
// BM=BN=256, BK=64, 512 thr = 8 waves (2M x 4N). Per-wave output is SPLIT
// across halves: rows {wm*64 in A-half0} u {128+wm*64 in A-half1}, cols
// {wn*32 in B-half0} u {128+wn*32 in B-half1} -> progressive half-tile
// consumption: ph0 reads A0+B0 (12 ds_read_b128), ph1 +B1 (4), ph2 +A1 (8),
// ph3 none. One half-tile (2 global_load_lds) staged per phase; counted
// vmcnt(4) at ends of phases 0/1/3 (4-8 loads always in flight, never
// drained); 2 barriers/phase; setprio(1) around each 16-MFMA cluster.
// LDS: 2 sets x 2 halves x (2 regions x 4096) elems per matrix = 128 KiB.
// 3-bit XOR chunk swizzle (phys = chunk ^ (row&7)) on both global source
// and read side; region stride 8192B keeps rows at 64B stride within a
// region -> uniform 8 words/bank on every ds_read_b128 (conflict-free).

#define PJ_BAR()  __builtin_amdgcn_s_barrier()
#define PJ_LG0()  asm volatile("s_waitcnt lgkmcnt(0)" ::: "memory")
#define PJ_VM(N)  asm volatile("s_waitcnt vmcnt(" #N ")" ::: "memory")
#define PJ_LA(S,H) do { _Pragma("unroll") for (int mt_ = 0; mt_ < 4; ++mt_) { \
    af[mt_][0] = *(const bf16x8*)&As[((S)*2+(H))*8192 + aof0 + mt_*512];      \
    af[mt_][1] = *(const bf16x8*)&As[((S)*2+(H))*8192 + aof1 + mt_*512]; } } while(0)
#define PJ_LB(DST,S,H) do { _Pragma("unroll") for (int nt_ = 0; nt_ < 2; ++nt_) { \
    DST[nt_][0] = *(const bf16x8*)&Bs[((S)*2+(H))*8192 + bof0 + nt_*512];         \
    DST[nt_][1] = *(const bf16x8*)&Bs[((S)*2+(H))*8192 + bof1 + nt_*512]; } } while(0)
#define PJ_SA(S,H,KO) do {                                              \
    lds_cp16(gA[H][0] + (KO), &As[((S)*2+(H))*8192 + ldst]);            \
    lds_cp16(gA[H][1] + (KO), &As[((S)*2+(H))*8192 + 4096 + ldst]); } while(0)
#define PJ_SB(S,H,KO) do {                                              \
    lds_cp16(gB[H][0] + (KO), &Bs[((S)*2+(H))*8192 + ldst]);            \
    lds_cp16(gB[H][1] + (KO), &Bs[((S)*2+(H))*8192 + 4096 + ldst]); } while(0)
#define PJ_MM(MH,NH,BFR) do {                                           \
    __builtin_amdgcn_s_setprio(1);                                      \
    _Pragma("unroll") for (int mt_ = 0; mt_ < 4; ++mt_)                 \
    _Pragma("unroll") for (int nt_ = 0; nt_ < 2; ++nt_) {               \
      acc[(MH)*4+mt_][(NH)*2+nt_] = __builtin_amdgcn_mfma_f32_16x16x32_bf16( \
          af[mt_][0], BFR[nt_][0], acc[(MH)*4+mt_][(NH)*2+nt_], 0, 0, 0);    \
      acc[(MH)*4+mt_][(NH)*2+nt_] = __builtin_amdgcn_mfma_f32_16x16x32_bf16( \
          af[mt_][1], BFR[nt_][1], acc[(MH)*4+mt_][(NH)*2+nt_], 0, 0, 0); }  \
    __builtin_amdgcn_s_setprio(0); } while(0)

__global__ __launch_bounds__(512, 2) void proj_kernel(
    const ushort* __restrict__ A, const ushort* __restrict__ Wt,
    const float* __restrict__ bf, const float* __restrict__ bg,
    const float* __restrict__ bx,
    ushort* __restrict__ q, ushort* __restrict__ k, ushort* __restrict__ v)
{
  __shared__ ushort As[2*2*8192];   // [set][half][region*4096] = 64 KB
  __shared__ ushort Bs[2*2*8192];   // 64 KB
  const int t = threadIdx.x;          // 0..511
  const int lane = t & 63;
  const int wid  = t >> 6;            // 0..7
  const int wm = wid >> 2;            // 0..1
  const int wn = wid & 3;             // 0..3

  // block -> tile via chunked XCD swizzle (768 = 8 XCDs x 96, bijective)
  const int wg = blockIdx.x;
  const int sw = (wg & 7) * 96 + (wg >> 3);
  const int mI = sw / 12, nI = sw - mI*12;
  const int m0 = mI * 256, n0 = nI * 256;     // n0 in [0,3072)
  const int seg = n0 >> 10;                   // 0:q 1:k 2:v
  const int nloc0 = n0 & 1023;

  // staging: thread t covers row srow (0..127) of a half, chunk slot t&3 in
  // region j. Pre-swizzled global chunk = (j*4 + (t&3)) ^ (srow&7).
  const int srow = t >> 2;
  const int ldst = t * 8;                     // elems within a region pair
  const ushort* gA[2][2];
  const ushort* gB[2][2];
  #pragma unroll
  for (int h = 0; h < 2; ++h)
    #pragma unroll
    for (int j = 0; j < 2; ++j) {
      const int lgc = ((j*4 + (t & 3)) ^ (srow & 7)) * 8;
      gA[h][j] = A  + (size_t)(m0 + h*128 + srow)*1024 + lgc;
      gB[h][j] = Wt + (size_t)(n0 + h*128 + srow)*1024 + lgc;
    }

  // read-side swizzled fragment offsets (elems within one half-buffer)
  const int quad = lane >> 4, l16 = lane & 15;
  const int phk0 = (0*4 + quad) ^ (l16 & 7);
  const int phk1 = (1*4 + quad) ^ (l16 & 7);
  const int aof0 = (phk0 >> 2)*4096 + (wm*64 + l16)*32 + (phk0 & 3)*8;
  const int aof1 = (phk1 >> 2)*4096 + (wm*64 + l16)*32 + (phk1 & 3)*8;
  const int bof0 = (phk0 >> 2)*4096 + (wn*32 + l16)*32 + (phk0 & 3)*8;
  const int bof1 = (phk1 >> 2)*4096 + (wn*32 + l16)*32 + (phk1 & 3)*8;

  f32x4 acc[8][4] = {};
  bf16x8 af[4][2], bA[2][2], bB[2][2];

  // prologue: stage tile 0 in consumption order A0,B0,B1,A1 (8 loads)
  PJ_SA(0,0,0); PJ_SB(0,0,0); PJ_SB(0,1,0); PJ_SA(0,1,0);
  PJ_VM(4);                      // A0,B0 landed; B1,A1 still in flight
  PJ_BAR();

  for (int tt = 0; tt < 15; ++tt) {
    const int cur = tt & 1, nxt = cur ^ 1;
    const int ko = (tt + 1) * 64;
    // ---- ph0: quadrant (0,0); reads A0+B0 (12); stage A0(t+1)
    PJ_LA(cur,0); PJ_LB(bA,cur,0); PJ_SA(nxt,0,ko);
    PJ_BAR(); PJ_LG0(); PJ_MM(0,0,bA); PJ_VM(4); PJ_BAR();
    // ---- ph1: quadrant (0,1); reads B1 (4); stage B0(t+1)
    PJ_LB(bB,cur,1); PJ_SB(nxt,0,ko);
    PJ_BAR(); PJ_LG0(); PJ_MM(0,1,bB); PJ_VM(4); PJ_BAR();
    // ---- ph2: quadrant (1,0); reads A1 (8); stage B1(t+1)
    PJ_LA(cur,1); PJ_SB(nxt,1,ko);
    PJ_BAR(); PJ_LG0(); PJ_MM(1,0,bA); PJ_BAR();
    // ---- ph3: quadrant (1,1); no reads; stage A1(t+1)
    PJ_SA(nxt,1,ko);
    PJ_BAR(); PJ_LG0(); PJ_MM(1,1,bB); PJ_VM(4); PJ_BAR();
  }
  // tail tile 15 (set 1), no staging; drain progressively
  PJ_LA(1,0); PJ_LB(bA,1,0);
  PJ_BAR(); PJ_LG0(); PJ_MM(0,0,bA); PJ_VM(2); PJ_BAR();
  PJ_LB(bB,1,1);
  PJ_BAR(); PJ_LG0(); PJ_MM(0,1,bB); PJ_VM(0); PJ_BAR();
  PJ_LA(1,1);
  PJ_BAR(); PJ_LG0(); PJ_MM(1,0,bA); PJ_BAR();
  PJ_BAR(); PJ_LG0(); PJ_MM(1,1,bB);

  // epilogue: bias + ReLU + bf16 store
  const float* bp = (seg == 0) ? bf : (seg == 1) ? bg : bx;
  ushort* op      = (seg == 0) ? q  : (seg == 1) ? k  : v;
  const int nbase = nloc0 + wn*32 + l16;
  float bv[4];
  #pragma unroll
  for (int ni = 0; ni < 4; ++ni)
    bv[ni] = bp[nbase + (ni>>1)*128 + (ni&1)*16];
  #pragma unroll
  for (int mi = 0; mi < 8; ++mi) {
    const int grow0 = m0 + (mi>>2)*128 + wm*64 + (mi&3)*16 + quad*4;
    #pragma unroll
    for (int rr = 0; rr < 4; ++rr) {
      const size_t rowoff = (size_t)(grow0 + rr) * 1024;
      #pragma unroll
      for (int ni = 0; ni < 4; ++ni)
        op[rowoff + nbase + (ni>>1)*128 + (ni&1)*16] =
            f2bf(fmaxf(acc[mi][ni][rr] + bv[ni], 0.f));
    }
  }
}

#undef PJ_BAR
#undef PJ_LG0
#undef PJ_VM
#undef PJ_LA
#undef PJ_LB
#undef PJ_SA
#undef PJ_SB
#undef PJ_MM

// ---------------- energy: NT GEMM, 64x128 tile, BK=64, 4 blocks/CU --------
// Grid = 16x8x16 = 2048 blocks; at 4/CU -> 1024 co-resident = exactly 2
// scheduling rounds. Wave w owns n-cols [w*32, w*32+32).
__global__ __launch_bounds__(256, 4) void energy_kernel(
    const ushort* __restrict__ Km, const ushort* __restrict__ Qm,
    ushort* __restrict__ E)
{
  __shared__ ushort As[64*64];    // [m(j) row][k]
  __shared__ ushort Bs[128*64];   // [n(i) row][k]
  const int t = threadIdx.x;
  const int wid = t >> 6, lane = t & 63;
  const int m0 = blockIdx.y * 64, n0 = blockIdx.x * 128;
  const int bz = blockIdx.z;
  const ushort* Ab = Km + (size_t)bz * C_ * D_;
  const ushort* Bb = Qm + (size_t)bz * C_ * D_;

  const int srow = t >> 3;                      // 0..31
  const int sch = ((t & 7) ^ (srow & 7)) * 8;   // +32 rows keeps row&7
  const ushort* gaBase = Ab + (size_t)(m0 + srow)*1024 + sch;
  const ushort* gbBase = Bb + (size_t)(n0 + srow)*1024 + sch;

  const int quad = lane >> 4, l16 = lane & 15;
  const int cx0 = ((0*4 + quad) ^ (l16 & 7)) * 8;
  const int cx1 = ((1*4 + quad) ^ (l16 & 7)) * 8;
  const int brow0 = (wid*32 + l16)*64;

  f32x4 acc[4][2] = {};

  for (int k0 = 0; k0 < 1024; k0 += 64) {
    // A: 64 rows -> 2 issues; B: 128 rows -> 4 issues
    #pragma unroll
    for (int i = 0; i < 2; ++i)
      lds_cp16(gaBase + (size_t)(i*32)*1024, As + (8*wid + 32*i)*64);
    #pragma unroll
    for (int i = 0; i < 4; ++i)
      lds_cp16(gbBase + (size_t)(i*32)*1024, Bs + (8*wid + 32*i)*64);
    gaBase += 64; gbBase += 64;
    __syncthreads();
    #pragma unroll
    for (int h = 0; h < 2; ++h) {
      const int cx = h ? cx1 : cx0;
      bf16x8 af[4], bfr[2];
      #pragma unroll
      for (int i = 0; i < 4; ++i)
        af[i] = *(const bf16x8*)&As[(i*16 + l16)*64 + cx];
      #pragma unroll
      for (int i = 0; i < 2; ++i)
        bfr[i] = *(const bf16x8*)&Bs[brow0 + i*16*64 + cx];
      #pragma unroll
      for (int mt = 0; mt < 4; ++mt)
        #pragma unroll
        for (int nt = 0; nt < 2; ++nt)
          acc[mt][nt] = __builtin_amdgcn_mfma_f32_16x16x32_bf16(
              af[mt], bfr[nt], acc[mt][nt], 0, 0, 0);
    }
    __syncthreads();
  }

  ushort* O = E + (size_t)bz * C_ * C_;
  const int gm_base = m0 + quad*4;              // j row
  const int gn_base = n0 + wid*32 + l16;        // i col
  #pragma unroll
  for (int mt = 0; mt < 4; ++mt)
    #pragma unroll
    for (int rr = 0; rr < 4; ++rr) {
      const size_t rowoff = (size_t)(gm_base + mt*16 + rr) * 1024;
      #pragma unroll
      for (int nt = 0; nt < 2; ++nt)
        O[rowoff + gn_base + nt*16] = f2bf(acc[mt][nt][rr]);
    }
}

// ---------------- pooling MLP via MFMA (BK=32) ----------------------------
__device__ __forceinline__ int fsw(int row){
  return (row & 3) ^ ((row >> 2) & 3);
}
__global__ __launch_bounds__(256) void pool_mfma_kernel(
    const ushort* __restrict__ A, const ushort* __restrict__ Bt,
    const float* __restrict__ b1, const float* __restrict__ W2,
    float* __restrict__ e2out)
{
  __shared__ ushort As[128*32];
  __shared__ ushort Bs[64*32];
  const int t = threadIdx.x;
  const int wid = t >> 6, lane = t & 63;
  const int m0 = blockIdx.x * 128;

  const int r = t >> 2;
  const int kc = ((t & 3) ^ fsw(r)) * 8;
  const ushort* ga0 = A + (size_t)(m0 + r)*1024 + kc;
  const ushort* ga1 = ga0 + (size_t)64*1024;
  const ushort* gb0 = Bt + (size_t)r*1024 + kc;
  ushort* lA = As + wid*512;
  ushort* lB = Bs + wid*512;

  const int quad = lane >> 4, l16 = lane & 15;
  const int fr = fsw(l16);
  const int am0 = (wid*32 + l16)*32 + ((quad ^ fr)*8);
  const int bn0 = l16*32 + ((quad ^ fr)*8);

  f32x4 acc[2][4] = {};

  for (int k0 = 0; k0 < 1024; k0 += 32) {
    lds_cp16(ga0, lA); lds_cp16(ga1, lA + 2048);
    lds_cp16(gb0, lB);
    ga0 += 32; ga1 += 32; gb0 += 32;
    __syncthreads();
    bf16x8 af[2], bfr[4];
    #pragma unroll
    for (int i = 0; i < 2; ++i) af[i] = *(const bf16x8*)&As[am0 + i*512];
    #pragma unroll
    for (int i = 0; i < 4; ++i) bfr[i] = *(const bf16x8*)&Bs[bn0 + i*512];
    #pragma unroll
    for (int mt = 0; mt < 2; ++mt)
      #pragma unroll
      for (int nt = 0; nt < 4; ++nt)
        acc[mt][nt] = __builtin_amdgcn_mfma_f32_16x16x32_bf16(
            af[mt], bfr[nt], acc[mt][nt], 0, 0, 0);
    __syncthreads();
  }

  float b1v[4], w2v[4];
  #pragma unroll
  for (int nt = 0; nt < 4; ++nt) {
    b1v[nt] = b1[nt*16 + l16];
    w2v[nt] = W2[nt*16 + l16];
  }
  #pragma unroll
  for (int mt = 0; mt < 2; ++mt)
    #pragma unroll
    for (int rr = 0; rr < 4; ++rr) {
      float h = 0.f;
      #pragma unroll
      for (int nt = 0; nt < 4; ++nt)
        h += fmaxf(acc[mt][nt][rr] + b1v[nt], 0.f) * w2v[nt];
      #pragma unroll
      for (int o = 1; o < 16; o <<= 1) h += __shfl_xor(h, o);
      if (l16 == 0)
        e2out[m0 + wid*32 + mt*16 + quad*4 + rr] = h;
    }
}

// ---------------- fused row-softmax + weighted column-sum (bf16 E) --------
__global__ __launch_bounds__(256) void fused_sm_kernel(
    const ushort* __restrict__ E, const float* __restrict__ w,
    float* __restrict__ u_part)
{
  __shared__ float ul[4][1024];
  const int b = blockIdx.y;
  const int strip = blockIdx.x;       // 0..63
  const int t = threadIdx.x, wv = t >> 6, lane = t & 63;
  const ushort* Eb = E + (size_t)b*C_*C_;
  const float* wb = w + (size_t)b*C_;
  float acc[2][8] = {};               // i = c*512 + lane*8 + k
  #pragma unroll
  for (int rj = 0; rj < 4; ++rj) {
    const int j = strip*16 + wv*4 + rj;
    const ushort* row = Eb + (size_t)j*C_;
    float vv[2][8];
    float m = -1e30f;
    #pragma unroll
    for (int c = 0; c < 2; ++c) {
      ushortx8 h = *(const ushortx8*)&row[c*512 + lane*8];
      #pragma unroll
      for (int kk = 0; kk < 8; ++kk) {
        vv[c][kk] = bf2f(h[kk]);
        m = fmaxf(m, vv[c][kk]);
      }
    }
    m = wave_max(m);
    float e[2][8];
    float s = 0.f;
    #pragma unroll
    for (int c = 0; c < 2; ++c)
      #pragma unroll
      for (int kk = 0; kk < 8; ++kk) {
        e[c][kk] = expf(vv[c][kk] - m);
        s += e[c][kk];
      }
    s = wave_sum(s);
    const float sc = wb[j] / s;
    #pragma unroll
    for (int c = 0; c < 2; ++c)
      #pragma unroll
      for (int kk = 0; kk < 8; ++kk) acc[c][kk] += sc * e[c][kk];
  }
  #pragma unroll
  for (int c = 0; c < 2; ++c)
    #pragma unroll
    for (int k4 = 0; k4 < 2; ++k4) {
      float4 o;
      o.x = acc[c][k4*4+0]; o.y = acc[c][k4*4+1];
      o.z = acc[c][k4*4+2]; o.w = acc[c][k4*4+3];
      *(float4*)&ul[wv][c*512 + lane*8 + k4*4] = o;
    }
  __syncthreads();
  float4 r0 = *(float4*)&ul[0][t*4];
  float4 r1 = *(float4*)&ul[1][t*4];
  float4 r2 = *(float4*)&ul[2][t*4];
  float4 r3 = *(float4*)&ul[3][t*4];
  float4 o;
  o.x = r0.x+r1.x+r2.x+r3.x; o.y = r0.y+r1.y+r2.y+r3.y;
  o.z = r0.z+r1.z+r2.z+r3.z; o.w = r0.w+r1.w+r2.w+r3.w;
  *(float4*)&u_part[((size_t)strip*B_ + b)*C_ + t*4] = o;
}

// ---------------- pooling softmax ----------------
__global__ __launch_bounds__(256) void softmax_w_kernel(
    const float* __restrict__ e2in, float* __restrict__ w)
{
  __shared__ float redm[4];
  __shared__ float reds[4];
  const int b = blockIdx.x, t = threadIdx.x;
  const int lane = t & 63, wid = t >> 6;
  const float* row = e2in + (size_t)b*C_;
  float4 v = *(const float4*)&row[t*4];
  float m = fmaxf(fmaxf(v.x, v.y), fmaxf(v.z, v.w));
  m = wave_max(m);
  if (lane == 0) redm[wid] = m;
  __syncthreads();
  m = fmaxf(fmaxf(redm[0], redm[1]), fmaxf(redm[2], redm[3]));
  float e0 = expf(v.x - m), e1 = expf(v.y - m);
  float e2 = expf(v.z - m), e3 = expf(v.w - m);
  float s = e0 + e1 + e2 + e3;
  s = wave_sum(s);
  if (lane == 0) reds[wid] = s;
  __syncthreads();
  s = reds[0] + reds[1] + reds[2] + reds[3];
  const float inv = 1.0f / s;
  float4 o; o.x = e0*inv; o.y = e1*inv; o.z = e2*inv; o.w = e3*inv;
  *(float4*)&w[(size_t)b*C_ + t*4] = o;
}

// ---------------- final reduction: u-combine fused in, split over i -------
__global__ __launch_bounds__(256) void final_part_kernel(
    const ushort* __restrict__ X, const ushort* __restrict__ V,
    const float* __restrict__ u_part, const float* __restrict__ w,
    const float* __restrict__ gamma, float* __restrict__ fpart)
{
  const int b = blockIdx.x, s = blockIdx.y;    // i in [s*16, s*16+16)
  const int t = threadIdx.x;
  __shared__ float red[16][17];
  __shared__ float us[16];
  {
    const int ii = t & 15, g = t >> 4;         // g sums 4 strips
    float p = 0.f;
    #pragma unroll
    for (int q2 = 0; q2 < 4; ++q2) {
      const int sp = g*4 + q2;
      p += u_part[((size_t)sp*B_ + b)*C_ + s*16 + ii];
    }
    red[ii][g] = p;
  }
  __syncthreads();
  if (t < 16) {
    float s2 = 0.f;
    #pragma unroll
    for (int g = 0; g < 16; ++g) s2 += red[t][g];
    us[t] = s2;
  }
  __syncthreads();

  const int d0 = t * 4;
  const ushort* xb = X + (size_t)b*C_*D_;
  const ushort* vb = V + (size_t)b*C_*D_;
  const float* wb = w + (size_t)b*C_;
  float4 av = {0,0,0,0}, ax = {0,0,0,0};
  #pragma unroll
  for (int ii = 0; ii < 16; ++ii) {
    const int i = s*16 + ii;
    const float ui = us[ii], wi = wb[i];
    ushort4 vv = *(const ushort4*)&vb[(size_t)i*D_ + d0];
    ushort4 xv = *(const ushort4*)&xb[(size_t)i*D_ + d0];
    av.x += ui*bf2f(vv.x); av.y += ui*bf2f(vv.y);
    av.z += ui*bf2f(vv.z); av.w += ui*bf2f(vv.w);
    ax.x += wi*bf2f(xv.x); ax.y += wi*bf2f(xv.y);
    ax.z += wi*bf2f(xv.z); ax.w += wi*bf2f(xv.w);
  }
  const float g = gamma[0];
  float4 o;
  o.x = g*av.x + ax.x; o.y = g*av.y + ax.y;
  o.z = g*av.z + ax.z; o.w = g*av.w + ax.w;
  *(float4*)&fpart[((size_t)s*B_ + b)*D_ + d0] = o;
}

__global__ __launch_bounds__(256) void final_combine_kernel(
    const float* __restrict__ fpart, float* __restrict__ out)
{
  const int idx = blockIdx.x*256 + threadIdx.x;   // over B_*D_
  float s = 0.f;
  #pragma unroll 8
  for (int sp = 0; sp < 64; ++sp) s += fpart[(size_t)sp*B_*D_ + idx];
  out[idx] = s;
}

extern "C" void kernel_launch(void* const* d_in, const int* in_sizes, int n_in,
                              void* d_out, int out_size, void* d_ws, size_t ws_size,
                              hipStream_t stream) {
  (void)in_sizes; (void)n_in; (void)out_size; (void)ws_size;
  const float* x  = (const float*)d_in[0];
  const float* Wf = (const float*)d_in[1];
  const float* bf = (const float*)d_in[2];
  const float* Wg = (const float*)d_in[3];
  const float* bg = (const float*)d_in[4];
  const float* Wx = (const float*)d_in[5];
  const float* bx = (const float*)d_in[6];
  const float* W1 = (const float*)d_in[7];
  const float* b1 = (const float*)d_in[8];
  const float* W2 = (const float*)d_in[9];
  const float* gamma = (const float*)d_in[11];
  float* out = (float*)d_out;

  // workspace layout (~140 MB total)
  ushort* x_bf = (ushort*)d_ws;                  // 32 MB
  ushort* wt   = x_bf + (size_t)M_*D_;           // 6 MB (Wf^T|Wg^T|Wx^T contiguous)
  ushort* w1t  = wt + (size_t)3*D_*D_;           // 128 KB
  ushort* q_bf = w1t + (size_t)H_*D_;            // 32 MB
  ushort* k_bf = q_bf + (size_t)M_*D_;           // 32 MB
  ushort* v_bf = k_bf + (size_t)M_*D_;           // 32 MB
  ushort* E    = v_bf + (size_t)M_*D_;           // 32 MB (bf16, all batches)
  float*  e2b  = (float*)(E + (size_t)B_*C_*C_); // 64 KB
  float*  wbuf = e2b + M_;                       // 64 KB
  float*  u_part = wbuf + M_;                    // 4 MB
  float*  fpart  = (float*)E;                    // alias: E dead after fused_sm

  // prep: x->bf16 + weight transposes, one launch
  prep_kernel<<<dim3(16384+3072+64), 256, 0, stream>>>(
      x, Wf, Wg, Wx, W1, x_bf, wt, w1t);

  // merged q/k/v projection (256^2 8-phase bf16 MFMA, 768 blocks)
  proj_kernel<<<dim3(768), 512, 0, stream>>>(x_bf, wt, bf, bg, bx,
                                             q_bf, k_bf, v_bf);

  // pooling weights (MFMA MLP + softmax)
  pool_mfma_kernel<<<dim3(M_/128), 256, 0, stream>>>(x_bf, w1t, b1, W2, e2b);
  softmax_w_kernel<<<dim3(B_), 256, 0, stream>>>(e2b, wbuf);

  // energy (64x128 tile, 4 blocks/CU, exact 2 rounds) + fused softmax/colsum
  energy_kernel<<<dim3(8,16,B_), 256, 0, stream>>>(k_bf, q_bf, E);
  fused_sm_kernel<<<dim3(64,B_), 256, 0, stream>>>(E, wbuf, u_part);

  // final: u-combine + split-i reduction into fpart, then combine
  final_part_kernel<<<dim3(B_,64), 256, 0, stream>>>(x_bf, v_bf, u_part, wbuf,
                                                     gamma, fpart);
  final_combine_kernel<<<dim3(M_/256), 256, 0, stream>>>(fpart, out);
}

// Round 5
// 314.058 us; speedup vs baseline: 1.1078x; 1.0794x over previous
//
#include <hip/hip_runtime.h>

#define B_ 16
#define C_ 1024
#define D_ 1024
#define H_ 64
#define M_ (B_*C_)   // 16384

typedef __attribute__((ext_vector_type(8))) short bf16x8;
typedef __attribute__((ext_vector_type(8))) unsigned short ushortx8;
typedef __attribute__((ext_vector_type(4))) float f32x4;

__device__ __forceinline__ float wave_max(float v){
  #pragma unroll
  for (int o = 32; o > 0; o >>= 1) v = fmaxf(v, __shfl_xor(v, o));
  return v;
}
__device__ __forceinline__ float wave_sum(float v){
  #pragma unroll
  for (int o = 32; o > 0; o >>= 1) v += __shfl_xor(v, o);
  return v;
}

// fp32 -> bf16 (RNE)
__device__ __forceinline__ ushort f2bf(float f){
  union { float f; unsigned u; } a; a.f = f;
  unsigned r = a.u + 0x7fff + ((a.u >> 16) & 1);
  return (ushort)(r >> 16);
}
__device__ __forceinline__ float bf2f(ushort h){
  union { unsigned u; float f; } a; a.u = ((unsigned)h) << 16; return a.f;
}

// async global->LDS, 16 B per lane; LDS dest is wave-uniform base + lane*16.
__device__ __forceinline__ void lds_cp16(const ushort* g, ushort* l){
  __builtin_amdgcn_global_load_lds(
      (const __attribute__((address_space(1))) void*)g,
      (__attribute__((address_space(3))) void*)l, 16, 0, 0);
}

// ---------------- merged prep: cvt(x) + weight transposes -----------------
__global__ __launch_bounds__(256) void prep_kernel(
    const float* __restrict__ x, const float* __restrict__ Wf,
    const float* __restrict__ Wg, const float* __restrict__ Wx,
    const float* __restrict__ W1,
    ushort* __restrict__ x_bf, ushort* __restrict__ wt,
    ushort* __restrict__ w1t)
{
  __shared__ float tile[32][33];
  const int blk = blockIdx.x;
  const int t = threadIdx.x;
  if (blk < 16384) {                       // cvt: x -> bf16, 4 elems/thread
    const int i = blk*256 + t;
    float4 v = ((const float4*)x)[i];
    ushort4 o;
    o.x = f2bf(v.x); o.y = f2bf(v.y); o.z = f2bf(v.z); o.w = f2bf(v.w);
    ((ushort4*)x_bf)[i] = o;
  } else if (blk < 16384 + 3072) {         // tconv of Wf/Wg/Wx -> wt[z]
    const int bb = blk - 16384;
    const int z = bb >> 10, rem = bb & 1023;
    const int n0 = (rem & 31)*32, k0 = (rem >> 5)*32;
    const float* W = (z == 0) ? Wf : (z == 1) ? Wg : Wx;
    ushort* Out = wt + (size_t)z*D_*D_;
    const int tx = t & 31, ty = t >> 5;
    #pragma unroll
    for (int i = 0; i < 32; i += 8)
      tile[ty+i][tx] = W[(size_t)(k0+ty+i)*D_ + n0+tx];
    __syncthreads();
    #pragma unroll
    for (int i = 0; i < 32; i += 8)
      Out[(size_t)(n0+ty+i)*D_ + k0+tx] = f2bf(tile[tx][ty+i]);
  } else {                                 // tconv of W1 (1024x64) -> w1t
    const int bb = blk - 16384 - 3072;
    const int n0 = (bb & 1)*32, k0 = (bb >> 1)*32;
    const int tx = t & 31, ty = t >> 5;
    #pragma unroll
    for (int i = 0; i < 32; i += 8)
      tile[ty+i][tx] = W1[(size_t)(k0+ty+i)*H_ + n0+tx];
    __syncthreads();
    #pragma unroll
    for (int i = 0; i < 32; i += 8)
      w1t[(size_t)(n0+ty+i)*D_ + k0+tx] = f2bf(tile[tx][ty+i]);
  }
}

// ---------------- merged QKV projection: 256^2, 8-phase schedule ----------
// R5 = R4 schedule with the PROVEN conflict-free LDS geometry (R0's):
// rows of 64 bf16 (128 B = all 32 banks), 3-bit chunk XOR
// phk = (h*4+quad)^(l16&7) -> quarter-wave covers all 8 16B slots,
// 2 lanes/slot (free). R4's 64B-row + 2-bit-XOR layout was a 4-way
// conflict (9.4M SQ_LDS_BANK_CONFLICT measured); this is the only change.
// Schedule (unchanged): BM=BN=256, BK=64, 512 thr = 8 waves (2Mx4N);
// 4 quadrant-phases/tile with progressive half-tile consumption
// (ph0: A0+B0 12 ds_reads, ph1: +B1 4, ph2: +A1 8, ph3: 0); one half-tile
// (2 global_load_lds) staged per phase; counted vmcnt(4) at ends of
// phases 0/1/3 (never drained in-loop); 2 barriers/phase; setprio around
// each 16-MFMA cluster. LDS: 2 sets x [256][64] per matrix = 128 KiB.

#define PJ_BAR()  __builtin_amdgcn_s_barrier()
#define PJ_LG0()  asm volatile("s_waitcnt lgkmcnt(0)" ::: "memory")
#define PJ_VM(N)  asm volatile("s_waitcnt vmcnt(" #N ")" ::: "memory")
#define PJ_LA(S,H) do { _Pragma("unroll") for (int mt_ = 0; mt_ < 4; ++mt_) { \
    af[mt_][0] = *(const bf16x8*)&As[(S)*16384 + (H)*8192 + arow + mt_*1024 + cxa0]; \
    af[mt_][1] = *(const bf16x8*)&As[(S)*16384 + (H)*8192 + arow + mt_*1024 + cxa1]; \
  } } while(0)
#define PJ_LB(DST,S,H) do { _Pragma("unroll") for (int nt_ = 0; nt_ < 2; ++nt_) { \
    DST[nt_][0] = *(const bf16x8*)&Bs[(S)*16384 + (H)*8192 + brow + nt_*1024 + cxa0]; \
    DST[nt_][1] = *(const bf16x8*)&Bs[(S)*16384 + (H)*8192 + brow + nt_*1024 + cxa1]; \
  } } while(0)
#define PJ_SA(S,H,KO) do {                                                  \
    lds_cp16(gA[H][0] + (KO), &As[(S)*16384 + (H)*8192 + ldst]);            \
    lds_cp16(gA[H][1] + (KO), &As[(S)*16384 + (H)*8192 + 4096 + ldst]); } while(0)
#define PJ_SB(S,H,KO) do {                                                  \
    lds_cp16(gB[H][0] + (KO), &Bs[(S)*16384 + (H)*8192 + ldst]);            \
    lds_cp16(gB[H][1] + (KO), &Bs[(S)*16384 + (H)*8192 + 4096 + ldst]); } while(0)
#define PJ_MM(MH,NH,BFR) do {                                           \
    __builtin_amdgcn_s_setprio(1);                                      \
    _Pragma("unroll") for (int mt_ = 0; mt_ < 4; ++mt_)                 \
    _Pragma("unroll") for (int nt_ = 0; nt_ < 2; ++nt_) {               \
      acc[(MH)*4+mt_][(NH)*2+nt_] = __builtin_amdgcn_mfma_f32_16x16x32_bf16( \
          af[mt_][0], BFR[nt_][0], acc[(MH)*4+mt_][(NH)*2+nt_], 0, 0, 0);    \
      acc[(MH)*4+mt_][(NH)*2+nt_] = __builtin_amdgcn_mfma_f32_16x16x32_bf16( \
          af[mt_][1], BFR[nt_][1], acc[(MH)*4+mt_][(NH)*2+nt_], 0, 0, 0); }  \
    __builtin_amdgcn_s_setprio(0); } while(0)

__global__ __launch_bounds__(512, 2) void proj_kernel(
    const ushort* __restrict__ A, const ushort* __restrict__ Wt,
    const float* __restrict__ bf, const float* __restrict__ bg,
    const float* __restrict__ bx,
    ushort* __restrict__ q, ushort* __restrict__ k, ushort* __restrict__ v)
{
  __shared__ ushort As[2*16384];   // [set][256 rows][64 elems] = 64 KB
  __shared__ ushort Bs[2*16384];   // 64 KB
  const int t = threadIdx.x;          // 0..511
  const int lane = t & 63;
  const int wid  = t >> 6;            // 0..7
  const int wm = wid >> 2;            // 0..1
  const int wn = wid & 3;             // 0..3

  // block -> tile via chunked XCD swizzle (768 = 8 XCDs x 96, bijective)
  const int wg = blockIdx.x;
  const int sw = (wg & 7) * 96 + (wg >> 3);
  const int mI = sw / 12, nI = sw - mI*12;
  const int m0 = mI * 256, n0 = nI * 256;     // n0 in [0,3072)
  const int seg = n0 >> 10;                   // 0:q 1:k 2:v
  const int nloc0 = n0 & 1023;

  // staging: thread t loads 16B of row srow=t>>3 (0..63 per issue; +64-row
  // issues preserve srow&7), chunk slot t&7 pre-swizzled by srow&7.
  const int srow = t >> 3;
  const int schunk = ((t & 7) ^ (srow & 7)) * 8;
  const int ldst = t * 8;                     // linear dest, 16B/thread
  const ushort* gA[2][2];                     // [half][64-row sub-block]
  const ushort* gB[2][2];
  #pragma unroll
  for (int h = 0; h < 2; ++h)
    #pragma unroll
    for (int j = 0; j < 2; ++j) {
      gA[h][j] = A  + (size_t)(m0 + h*128 + j*64 + srow)*1024 + schunk;
      gB[h][j] = Wt + (size_t)(n0 + h*128 + j*64 + srow)*1024 + schunk;
    }

  // read-side fragment offsets (R0-proven): row*64 + ((h*4+quad)^(l16&7))*8
  const int quad = lane >> 4, l16 = lane & 15;
  const int cxa0 = ((0*4 + quad) ^ (l16 & 7)) * 8;
  const int cxa1 = ((1*4 + quad) ^ (l16 & 7)) * 8;
  const int arow = (wm*64 + l16) * 64;
  const int brow = (wn*32 + l16) * 64;

  f32x4 acc[8][4] = {};
  bf16x8 af[4][2], bA[2][2], bB[2][2];

  // prologue: stage tile 0 in consumption order A0,B0,B1,A1 (8 loads)
  PJ_SA(0,0,0); PJ_SB(0,0,0); PJ_SB(0,1,0); PJ_SA(0,1,0);
  PJ_VM(4);                      // A0,B0 landed; B1,A1 still in flight
  PJ_BAR();

  for (int tt = 0; tt < 15; ++tt) {
    const int cur = tt & 1, nxt = cur ^ 1;
    const int ko = (tt + 1) * 64;
    // ---- ph0: quadrant (0,0); reads A0+B0 (12); stage A0(t+1)
    PJ_LA(cur,0); PJ_LB(bA,cur,0); PJ_SA(nxt,0,ko);
    PJ_BAR(); PJ_LG0(); PJ_MM(0,0,bA); PJ_VM(4); PJ_BAR();
    // ---- ph1: quadrant (0,1); reads B1 (4); stage B0(t+1)
    PJ_LB(bB,cur,1); PJ_SB(nxt,0,ko);
    PJ_BAR(); PJ_LG0(); PJ_MM(0,1,bB); PJ_VM(4); PJ_BAR();
    // ---- ph2: quadrant (1,0); reads A1 (8); stage B1(t+1)
    PJ_LA(cur,1); PJ_SB(nxt,1,ko);
    PJ_BAR(); PJ_LG0(); PJ_MM(1,0,bA); PJ_BAR();
    // ---- ph3: quadrant (1,1); no reads; stage A1(t+1)
    PJ_SA(nxt,1,ko);
    PJ_BAR(); PJ_LG0(); PJ_MM(1,1,bB); PJ_VM(4); PJ_BAR();
  }
  // tail tile 15 (set 1), no staging; drain progressively
  PJ_LA(1,0); PJ_LB(bA,1,0);
  PJ_BAR(); PJ_LG0(); PJ_MM(0,0,bA); PJ_VM(2); PJ_BAR();
  PJ_LB(bB,1,1);
  PJ_BAR(); PJ_LG0(); PJ_MM(0,1,bB); PJ_VM(0); PJ_BAR();
  PJ_LA(1,1);
  PJ_BAR(); PJ_LG0(); PJ_MM(1,0,bA); PJ_BAR();
  PJ_BAR(); PJ_LG0(); PJ_MM(1,1,bB);

  // epilogue: bias + ReLU + bf16 store
  const float* bp = (seg == 0) ? bf : (seg == 1) ? bg : bx;
  ushort* op      = (seg == 0) ? q  : (seg == 1) ? k  : v;
  const int nbase = nloc0 + wn*32 + l16;
  float bv[4];
  #pragma unroll
  for (int ni = 0; ni < 4; ++ni)
    bv[ni] = bp[nbase + (ni>>1)*128 + (ni&1)*16];
  #pragma unroll
  for (int mi = 0; mi < 8; ++mi) {
    const int grow0 = m0 + (mi>>2)*128 + wm*64 + (mi&3)*16 + quad*4;
    #pragma unroll
    for (int rr = 0; rr < 4; ++rr) {
      const size_t rowoff = (size_t)(grow0 + rr) * 1024;
      #pragma unroll
      for (int ni = 0; ni < 4; ++ni)
        op[rowoff + nbase + (ni>>1)*128 + (ni&1)*16] =
            f2bf(fmaxf(acc[mi][ni][rr] + bv[ni], 0.f));
    }
  }
}

#undef PJ_BAR
#undef PJ_LG0
#undef PJ_VM
#undef PJ_LA
#undef PJ_LB
#undef PJ_SA
#undef PJ_SB
#undef PJ_MM

// ---------------- energy: NT GEMM, 64x128 tile, BK=64, 4 blocks/CU --------
// Grid = 16x8x16 = 2048 blocks; at 4/CU -> 1024 co-resident = exactly 2
// scheduling rounds. Wave w owns n-cols [w*32, w*32+32).
__global__ __launch_bounds__(256, 4) void energy_kernel(
    const ushort* __restrict__ Km, const ushort* __restrict__ Qm,
    ushort* __restrict__ E)
{
  __shared__ ushort As[64*64];    // [m(j) row][k]
  __shared__ ushort Bs[128*64];   // [n(i) row][k]
  const int t = threadIdx.x;
  const int wid = t >> 6, lane = t & 63;
  const int m0 = blockIdx.y * 64, n0 = blockIdx.x * 128;
  const int bz = blockIdx.z;
  const ushort* Ab = Km + (size_t)bz * C_ * D_;
  const ushort* Bb = Qm + (size_t)bz * C_ * D_;

  const int srow = t >> 3;                      // 0..31
  const int sch = ((t & 7) ^ (srow & 7)) * 8;   // +32 rows keeps row&7
  const ushort* gaBase = Ab + (size_t)(m0 + srow)*1024 + sch;
  const ushort* gbBase = Bb + (size_t)(n0 + srow)*1024 + sch;

  const int quad = lane >> 4, l16 = lane & 15;
  const int cx0 = ((0*4 + quad) ^ (l16 & 7)) * 8;
  const int cx1 = ((1*4 + quad) ^ (l16 & 7)) * 8;
  const int brow0 = (wid*32 + l16)*64;

  f32x4 acc[4][2] = {};

  for (int k0 = 0; k0 < 1024; k0 += 64) {
    // A: 64 rows -> 2 issues; B: 128 rows -> 4 issues
    #pragma unroll
    for (int i = 0; i < 2; ++i)
      lds_cp16(gaBase + (size_t)(i*32)*1024, As + (8*wid + 32*i)*64);
    #pragma unroll
    for (int i = 0; i < 4; ++i)
      lds_cp16(gbBase + (size_t)(i*32)*1024, Bs + (8*wid + 32*i)*64);
    gaBase += 64; gbBase += 64;
    __syncthreads();
    #pragma unroll
    for (int h = 0; h < 2; ++h) {
      const int cx = h ? cx1 : cx0;
      bf16x8 af[4], bfr[2];
      #pragma unroll
      for (int i = 0; i < 4; ++i)
        af[i] = *(const bf16x8*)&As[(i*16 + l16)*64 + cx];
      #pragma unroll
      for (int i = 0; i < 2; ++i)
        bfr[i] = *(const bf16x8*)&Bs[brow0 + i*16*64 + cx];
      #pragma unroll
      for (int mt = 0; mt < 4; ++mt)
        #pragma unroll
        for (int nt = 0; nt < 2; ++nt)
          acc[mt][nt] = __builtin_amdgcn_mfma_f32_16x16x32_bf16(
              af[mt], bfr[nt], acc[mt][nt], 0, 0, 0);
    }
    __syncthreads();
  }

  ushort* O = E + (size_t)bz * C_ * C_;
  const int gm_base = m0 + quad*4;              // j row
  const int gn_base = n0 + wid*32 + l16;        // i col
  #pragma unroll
  for (int mt = 0; mt < 4; ++mt)
    #pragma unroll
    for (int rr = 0; rr < 4; ++rr) {
      const size_t rowoff = (size_t)(gm_base + mt*16 + rr) * 1024;
      #pragma unroll
      for (int nt = 0; nt < 2; ++nt)
        O[rowoff + gn_base + nt*16] = f2bf(acc[mt][nt][rr]);
    }
}

// ---------------- pooling MLP via MFMA (BK=32) ----------------------------
__device__ __forceinline__ int fsw(int row){
  return (row & 3) ^ ((row >> 2) & 3);
}
__global__ __launch_bounds__(256) void pool_mfma_kernel(
    const ushort* __restrict__ A, const ushort* __restrict__ Bt,
    const float* __restrict__ b1, const float* __restrict__ W2,
    float* __restrict__ e2out)
{
  __shared__ ushort As[128*32];
  __shared__ ushort Bs[64*32];
  const int t = threadIdx.x;
  const int wid = t >> 6, lane = t & 63;
  const int m0 = blockIdx.x * 128;

  const int r = t >> 2;
  const int kc = ((t & 3) ^ fsw(r)) * 8;
  const ushort* ga0 = A + (size_t)(m0 + r)*1024 + kc;
  const ushort* ga1 = ga0 + (size_t)64*1024;
  const ushort* gb0 = Bt + (size_t)r*1024 + kc;
  ushort* lA = As + wid*512;
  ushort* lB = Bs + wid*512;

  const int quad = lane >> 4, l16 = lane & 15;
  const int fr = fsw(l16);
  const int am0 = (wid*32 + l16)*32 + ((quad ^ fr)*8);
  const int bn0 = l16*32 + ((quad ^ fr)*8);

  f32x4 acc[2][4] = {};

  for (int k0 = 0; k0 < 1024; k0 += 32) {
    lds_cp16(ga0, lA); lds_cp16(ga1, lA + 2048);
    lds_cp16(gb0, lB);
    ga0 += 32; ga1 += 32; gb0 += 32;
    __syncthreads();
    bf16x8 af[2], bfr[4];
    #pragma unroll
    for (int i = 0; i < 2; ++i) af[i] = *(const bf16x8*)&As[am0 + i*512];
    #pragma unroll
    for (int i = 0; i < 4; ++i) bfr[i] = *(const bf16x8*)&Bs[bn0 + i*512];
    #pragma unroll
    for (int mt = 0; mt < 2; ++mt)
      #pragma unroll
      for (int nt = 0; nt < 4; ++nt)
        acc[mt][nt] = __builtin_amdgcn_mfma_f32_16x16x32_bf16(
            af[mt], bfr[nt], acc[mt][nt], 0, 0, 0);
    __syncthreads();
  }

  float b1v[4], w2v[4];
  #pragma unroll
  for (int nt = 0; nt < 4; ++nt) {
    b1v[nt] = b1[nt*16 + l16];
    w2v[nt] = W2[nt*16 + l16];
  }
  #pragma unroll
  for (int mt = 0; mt < 2; ++mt)
    #pragma unroll
    for (int rr = 0; rr < 4; ++rr) {
      float h = 0.f;
      #pragma unroll
      for (int nt = 0; nt < 4; ++nt)
        h += fmaxf(acc[mt][nt][rr] + b1v[nt], 0.f) * w2v[nt];
      #pragma unroll
      for (int o = 1; o < 16; o <<= 1) h += __shfl_xor(h, o);
      if (l16 == 0)
        e2out[m0 + wid*32 + mt*16 + quad*4 + rr] = h;
    }
}

// ---------------- fused row-softmax + weighted column-sum (bf16 E) --------
__global__ __launch_bounds__(256) void fused_sm_kernel(
    const ushort* __restrict__ E, const float* __restrict__ w,
    float* __restrict__ u_part)
{
  __shared__ float ul[4][1024];
  const int b = blockIdx.y;
  const int strip = blockIdx.x;       // 0..63
  const int t = threadIdx.x, wv = t >> 6, lane = t & 63;
  const ushort* Eb = E + (size_t)b*C_*C_;
  const float* wb = w + (size_t)b*C_;
  float acc[2][8] = {};               // i = c*512 + lane*8 + k
  #pragma unroll
  for (int rj = 0; rj < 4; ++rj) {
    const int j = strip*16 + wv*4 + rj;
    const ushort* row = Eb + (size_t)j*C_;
    float vv[2][8];
    float m = -1e30f;
    #pragma unroll
    for (int c = 0; c < 2; ++c) {
      ushortx8 h = *(const ushortx8*)&row[c*512 + lane*8];
      #pragma unroll
      for (int kk = 0; kk < 8; ++kk) {
        vv[c][kk] = bf2f(h[kk]);
        m = fmaxf(m, vv[c][kk]);
      }
    }
    m = wave_max(m);
    float e[2][8];
    float s = 0.f;
    #pragma unroll
    for (int c = 0; c < 2; ++c)
      #pragma unroll
      for (int kk = 0; kk < 8; ++kk) {
        e[c][kk] = expf(vv[c][kk] - m);
        s += e[c][kk];
      }
    s = wave_sum(s);
    const float sc = wb[j] / s;
    #pragma unroll
    for (int c = 0; c < 2; ++c)
      #pragma unroll
      for (int kk = 0; kk < 8; ++kk) acc[c][kk] += sc * e[c][kk];
  }
  #pragma unroll
  for (int c = 0; c < 2; ++c)
    #pragma unroll
    for (int k4 = 0; k4 < 2; ++k4) {
      float4 o;
      o.x = acc[c][k4*4+0]; o.y = acc[c][k4*4+1];
      o.z = acc[c][k4*4+2]; o.w = acc[c][k4*4+3];
      *(float4*)&ul[wv][c*512 + lane*8 + k4*4] = o;
    }
  __syncthreads();
  float4 r0 = *(float4*)&ul[0][t*4];
  float4 r1 = *(float4*)&ul[1][t*4];
  float4 r2 = *(float4*)&ul[2][t*4];
  float4 r3 = *(float4*)&ul[3][t*4];
  float4 o;
  o.x = r0.x+r1.x+r2.x+r3.x; o.y = r0.y+r1.y+r2.y+r3.y;
  o.z = r0.z+r1.z+r2.z+r3.z; o.w = r0.w+r1.w+r2.w+r3.w;
  *(float4*)&u_part[((size_t)strip*B_ + b)*C_ + t*4] = o;
}

// ---------------- pooling softmax ----------------
__global__ __launch_bounds__(256) void softmax_w_kernel(
    const float* __restrict__ e2in, float* __restrict__ w)
{
  __shared__ float redm[4];
  __shared__ float reds[4];
  const int b = blockIdx.x, t = threadIdx.x;
  const int lane = t & 63, wid = t >> 6;
  const float* row = e2in + (size_t)b*C_;
  float4 v = *(const float4*)&row[t*4];
  float m = fmaxf(fmaxf(v.x, v.y), fmaxf(v.z, v.w));
  m = wave_max(m);
  if (lane == 0) redm[wid] = m;
  __syncthreads();
  m = fmaxf(fmaxf(redm[0], redm[1]), fmaxf(redm[2], redm[3]));
  float e0 = expf(v.x - m), e1 = expf(v.y - m);
  float e2 = expf(v.z - m), e3 = expf(v.w - m);
  float s = e0 + e1 + e2 + e3;
  s = wave_sum(s);
  if (lane == 0) reds[wid] = s;
  __syncthreads();
  s = reds[0] + reds[1] + reds[2] + reds[3];
  const float inv = 1.0f / s;
  float4 o; o.x = e0*inv; o.y = e1*inv; o.z = e2*inv; o.w = e3*inv;
  *(float4*)&w[(size_t)b*C_ + t*4] = o;
}

// ---------------- final reduction: u-combine fused in, split over i -------
__global__ __launch_bounds__(256) void final_part_kernel(
    const ushort* __restrict__ X, const ushort* __restrict__ V,
    const float* __restrict__ u_part, const float* __restrict__ w,
    const float* __restrict__ gamma, float* __restrict__ fpart)
{
  const int b = blockIdx.x, s = blockIdx.y;    // i in [s*16, s*16+16)
  const int t = threadIdx.x;
  __shared__ float red[16][17];
  __shared__ float us[16];
  {
    const int ii = t & 15, g = t >> 4;         // g sums 4 strips
    float p = 0.f;
    #pragma unroll
    for (int q2 = 0; q2 < 4; ++q2) {
      const int sp = g*4 + q2;
      p += u_part[((size_t)sp*B_ + b)*C_ + s*16 + ii];
    }
    red[ii][g] = p;
  }
  __syncthreads();
  if (t < 16) {
    float s2 = 0.f;
    #pragma unroll
    for (int g = 0; g < 16; ++g) s2 += red[t][g];
    us[t] = s2;
  }
  __syncthreads();

  const int d0 = t * 4;
  const ushort* xb = X + (size_t)b*C_*D_;
  const ushort* vb = V + (size_t)b*C_*D_;
  const float* wb = w + (size_t)b*C_;
  float4 av = {0,0,0,0}, ax = {0,0,0,0};
  #pragma unroll
  for (int ii = 0; ii < 16; ++ii) {
    const int i = s*16 + ii;
    const float ui = us[ii], wi = wb[i];
    ushort4 vv = *(const ushort4*)&vb[(size_t)i*D_ + d0];
    ushort4 xv = *(const ushort4*)&xb[(size_t)i*D_ + d0];
    av.x += ui*bf2f(vv.x); av.y += ui*bf2f(vv.y);
    av.z += ui*bf2f(vv.z); av.w += ui*bf2f(vv.w);
    ax.x += wi*bf2f(xv.x); ax.y += wi*bf2f(xv.y);
    ax.z += wi*bf2f(xv.z); ax.w += wi*bf2f(xv.w);
  }
  const float g = gamma[0];
  float4 o;
  o.x = g*av.x + ax.x; o.y = g*av.y + ax.y;
  o.z = g*av.z + ax.z; o.w = g*av.w + ax.w;
  *(float4*)&fpart[((size_t)s*B_ + b)*D_ + d0] = o;
}

__global__ __launch_bounds__(256) void final_combine_kernel(
    const float* __restrict__ fpart, float* __restrict__ out)
{
  const int idx = blockIdx.x*256 + threadIdx.x;   // over B_*D_
  float s = 0.f;
  #pragma unroll 8
  for (int sp = 0; sp < 64; ++sp) s += fpart[(size_t)sp*B_*D_ + idx];
  out[idx] = s;
}

extern "C" void kernel_launch(void* const* d_in, const int* in_sizes, int n_in,
                              void* d_out, int out_size, void* d_ws, size_t ws_size,
                              hipStream_t stream) {
  (void)in_sizes; (void)n_in; (void)out_size; (void)ws_size;
  const float* x  = (const float*)d_in[0];
  const float* Wf = (const float*)d_in[1];
  const float* bf = (const float*)d_in[2];
  const float* Wg = (const float*)d_in[3];
  const float* bg = (const float*)d_in[4];
  const float* Wx = (const float*)d_in[5];
  const float* bx = (const float*)d_in[6];
  const float* W1 = (const float*)d_in[7];
  const float* b1 = (const float*)d_in[8];
  const float* W2 = (const float*)d_in[9];
  const float* gamma = (const float*)d_in[11];
  float* out = (float*)d_out;

  // workspace layout (~140 MB total)
  ushort* x_bf = (ushort*)d_ws;                  // 32 MB
  ushort* wt   = x_bf + (size_t)M_*D_;           // 6 MB (Wf^T|Wg^T|Wx^T contiguous)
  ushort* w1t  = wt + (size_t)3*D_*D_;           // 128 KB
  ushort* q_bf = w1t + (size_t)H_*D_;            // 32 MB
  ushort* k_bf = q_bf + (size_t)M_*D_;           // 32 MB
  ushort* v_bf = k_bf + (size_t)M_*D_;           // 32 MB
  ushort* E    = v_bf + (size_t)M_*D_;           // 32 MB (bf16, all batches)
  float*  e2b  = (float*)(E + (size_t)B_*C_*C_); // 64 KB
  float*  wbuf = e2b + M_;                       // 64 KB
  float*  u_part = wbuf + M_;                    // 4 MB
  float*  fpart  = (float*)E;                    // alias: E dead after fused_sm

  // prep: x->bf16 + weight transposes, one launch
  prep_kernel<<<dim3(16384+3072+64), 256, 0, stream>>>(
      x, Wf, Wg, Wx, W1, x_bf, wt, w1t);

  // merged q/k/v projection (256^2 8-phase bf16 MFMA, 768 blocks)
  proj_kernel<<<dim3(768), 512, 0, stream>>>(x_bf, wt, bf, bg, bx,
                                             q_bf, k_bf, v_bf);

  // pooling weights (MFMA MLP + softmax)
  pool_mfma_kernel<<<dim3(M_/128), 256, 0, stream>>>(x_bf, w1t, b1, W2, e2b);
  softmax_w_kernel<<<dim3(B_), 256, 0, stream>>>(e2b, wbuf);

  // energy (64x128 tile, 4 blocks/CU, exact 2 rounds) + fused softmax/colsum
  energy_kernel<<<dim3(8,16,B_), 256, 0, stream>>>(k_bf, q_bf, E);
  fused_sm_kernel<<<dim3(64,B_), 256, 0, stream>>>(E, wbuf, u_part);

  // final: u-combine + split-i reduction into fpart, then combine
  final_part_kernel<<<dim3(B_,64), 256, 0, stream>>>(x_bf, v_bf, u_part, wbuf,
                                                     gamma, fpart);
  final_combine_kernel<<<dim3(M_/256), 256, 0, stream>>>(fpart, out);
}